// Round 1
// baseline (1714.950 us; speedup 1.0000x reference)
//
#include <hip/hip_runtime.h>
#include <stdint.h>

#define Mh   256
#define DIMx 128
#define Tt   128
#define Bb   256

typedef __attribute__((ext_vector_type(8))) short short8;  // 8 bf16 (4 VGPR)
typedef __attribute__((ext_vector_type(4))) float f32x4;

// ---- workspace layout (bytes) ----
static const size_t OFF_GH  = 0;         // gate hi frags [2][16][8][64][8] u16 = 262144
static const size_t OFF_GL  = 262144;    // gate lo frags                    = 262144
static const size_t OFF_H1H = 524288;    // Wh1 hi frags [16][8][64][8] u16  = 131072
static const size_t OFF_H1L = 655360;    // Wh1 lo frags                     = 131072
static const size_t OFF_WXH = 786432;    // Wx hi frags [3][16][4][64][8]    = 196608
static const size_t OFF_WXL = 983040;    // Wx lo frags                      = 196608
static const size_t OFF_P   = 1179648;   // P [3][128][256][256] f32 = 100663296
static const size_t WS_NEED = OFF_P + 3ull*Tt*Bb*Mh*4ull;

__device__ __forceinline__ f32x4 mfma16(short8 a, short8 b, f32x4 c){
  return __builtin_amdgcn_mfma_f32_16x16x32_bf16(a, b, c, 0, 0, 0);
}

// exact hi/lo split: v == bf16(hi) + bf16(lo) to ~2^-16 rel
__device__ __forceinline__ void split1(float v, uint16_t& hi, uint16_t& lo){
  uint32_t b = __float_as_uint(v);
  hi = (uint16_t)(b >> 16);
  float hf = __uint_as_float(b & 0xFFFF0000u);
  float lf = v - hf;                       // exact
  lo = (uint16_t)(__float_as_uint(lf) >> 16);
}

__device__ __forceinline__ void split8f(float4 v0, float4 v1, short8& hi, short8& lo){
  float vv[8] = {v0.x, v0.y, v0.z, v0.w, v1.x, v1.y, v1.z, v1.w};
  #pragma unroll
  for (int i = 0; i < 8; ++i){
    uint16_t h, l2; split1(vv[i], h, l2);
    hi[i] = (short)h; lo[i] = (short)l2;
  }
}

__device__ __forceinline__ float sigm(float v){ return 1.0f / (1.0f + __expf(-v)); }
__device__ __forceinline__ float tanhA(float v){
  float e = __expf(2.0f * v);              // inf-safe: e=inf -> 1, e=0 -> -1
  return 1.0f - 2.0f / (e + 1.0f);
}

// ---------------- kernel 0: weight prep (split + fragment packing) ----------------
// frag map (mfma_f32_16x16x32_bf16): lane l=16*g+c ; B-frag elem i -> B[k=32*kt+8*g+i][col=16*mt+c]
__global__ void prep_kernel(const float* __restrict__ Wz, const float* __restrict__ Wr,
                            const float* __restrict__ Wh1, const float* __restrict__ Wh2,
                            uint8_t* __restrict__ ws){
  int tid = blockIdx.x * 256 + threadIdx.x;
  uint16_t* gh  = (uint16_t*)(ws + OFF_GH);
  uint16_t* gl  = (uint16_t*)(ws + OFF_GL);
  uint16_t* h1h = (uint16_t*)(ws + OFF_H1H);
  uint16_t* h1l = (uint16_t*)(ws + OFF_H1L);
  uint16_t* wxh = (uint16_t*)(ws + OFF_WXH);
  uint16_t* wxl = (uint16_t*)(ws + OFF_WXL);
  if (tid < 16384){                      // gates (recurrent part, cols 0..255 of Wz/Wr)
    int l = tid & 63, kt = (tid >> 6) & 7, mt = (tid >> 9) & 15, mat = tid >> 13;
    int c = l & 15, g = l >> 4, m = mt*16 + c, k0 = kt*32 + g*8;
    const float* W = mat ? Wr : Wz;
    #pragma unroll
    for (int i = 0; i < 8; ++i){
      uint16_t h, lo2; split1(W[m*384 + k0 + i], h, lo2);
      gh[(size_t)tid*8 + i] = h; gl[(size_t)tid*8 + i] = lo2;
    }
  } else if (tid < 24576){               // Wh1
    int t2 = tid - 16384;
    int l = t2 & 63, kt = (t2 >> 6) & 7, mt = (t2 >> 9) & 15;
    int c = l & 15, g = l >> 4, m = mt*16 + c, k0 = kt*32 + g*8;
    #pragma unroll
    for (int i = 0; i < 8; ++i){
      uint16_t h, lo2; split1(Wh1[m*256 + k0 + i], h, lo2);
      h1h[(size_t)t2*8 + i] = h; h1l[(size_t)t2*8 + i] = lo2;
    }
  } else if (tid < 36864){               // input-projection weights (x part)
    int t3 = tid - 24576;
    int l = t3 & 63, kt = (t3 >> 6) & 3, mt = (t3 >> 8) & 15, mat = t3 >> 12;
    int c = l & 15, g = l >> 4, m = mt*16 + c, k0 = kt*32 + g*8;
    #pragma unroll
    for (int i = 0; i < 8; ++i){
      int k = k0 + i;
      float v = (mat == 0) ? Wz[m*384 + 256 + k]
              : (mat == 1) ? Wr[m*384 + 256 + k]
                           : Wh2[m*128 + k];
      uint16_t h, lo2; split1(v, h, lo2);
      wxh[(size_t)t3*8 + i] = h; wxl[(size_t)t3*8 + i] = lo2;
    }
  }
}

// ---------------- kernel 1: gather + input projections  P^T[mat][t][b][m] ----------------
// A = X^T (rows=b, k=d, loaded straight from topo), B = Wx^T frags (resident in regs)
__launch_bounds__(512, 2)
__global__ void proj_kernel(const int* __restrict__ x, const float* __restrict__ topo,
                            const float* __restrict__ bz, const float* __restrict__ br,
                            const float* __restrict__ bh, const uint8_t* __restrict__ ws,
                            float* __restrict__ P){
  int w = threadIdx.x >> 6, l = threadIdx.x & 63;
  int c = l & 15, g = l >> 4;
  int bt = blockIdx.x & 15, tg = blockIdx.x >> 4;
  int b0 = bt * 16;
  const uint16_t* wxh = (const uint16_t*)(ws + OFF_WXH);
  const uint16_t* wxl = (const uint16_t*)(ws + OFF_WXL);

  short8 BH[3][2][4], BL[3][2][4];
  #pragma unroll
  for (int mat = 0; mat < 3; ++mat)
    #pragma unroll
    for (int mtl = 0; mtl < 2; ++mtl){
      int mt = w*2 + mtl;
      #pragma unroll
      for (int kt = 0; kt < 4; ++kt){
        size_t o = ((((size_t)mat*16 + mt)*4 + kt)*64 + l)*8;
        BH[mat][mtl][kt] = *(const short8*)(wxh + o);
        BL[mat][mtl][kt] = *(const short8*)(wxl + o);
      }
    }
  float bias[3][2];
  #pragma unroll
  for (int mat = 0; mat < 3; ++mat){
    const float* bp = (mat == 0) ? bz : (mat == 1) ? br : bh;
    bias[mat][0] = bp[(w*2 + 0)*16 + c];
    bias[mat][1] = bp[(w*2 + 1)*16 + c];
  }
  int64_t tbase = (int64_t)x[b0 + (l & 15)] * (Tt * DIMx);

  for (int tt = 0; tt < 8; ++tt){
    int t = tg*8 + tt;
    const float* xp = topo + tbase + (int64_t)t * DIMx;
    f32x4 acc[3][2];
    #pragma unroll
    for (int mat = 0; mat < 3; ++mat)
      #pragma unroll
      for (int mtl = 0; mtl < 2; ++mtl){
        f32x4 a; a[0] = a[1] = a[2] = a[3] = bias[mat][mtl]; acc[mat][mtl] = a;
      }
    #pragma unroll
    for (int kt = 0; kt < 4; ++kt){
      float4 v0 = *(const float4*)(xp + kt*32 + g*8);
      float4 v1 = *(const float4*)(xp + kt*32 + g*8 + 4);
      short8 ahi, alo; split8f(v0, v1, ahi, alo);
      #pragma unroll
      for (int mat = 0; mat < 3; ++mat)
        #pragma unroll
        for (int mtl = 0; mtl < 2; ++mtl){
          acc[mat][mtl] = mfma16(ahi, BH[mat][mtl][kt], acc[mat][mtl]);
          acc[mat][mtl] = mfma16(ahi, BL[mat][mtl][kt], acc[mat][mtl]);
          acc[mat][mtl] = mfma16(alo, BH[mat][mtl][kt], acc[mat][mtl]);
        }
    }
    #pragma unroll
    for (int mat = 0; mat < 3; ++mat)
      #pragma unroll
      for (int mtl = 0; mtl < 2; ++mtl){
        int m0 = (w*2 + mtl)*16;
        #pragma unroll
        for (int i = 0; i < 4; ++i){
          P[(((size_t)mat*Tt + t)*Bb + (b0 + 4*g + i))*Mh + m0 + c] = acc[mat][mtl][i];
        }
      }
  }
}

// ---------------- kernel 2: sequential GRU (16 WGs x 16 batch cols) ----------------
// LDS: [0,114688) Wh1-hi frags (kt 0..6) ; [114688,131072) h^T f32 swizzled ; [131072,147456) s^T
__launch_bounds__(512, 2)
__global__ void gru_kernel(const uint8_t* __restrict__ ws, const float* __restrict__ P,
                           float* __restrict__ out){
  extern __shared__ uint8_t lds[];
  const int tx = threadIdx.x;
  const int w = tx >> 6, l = tx & 63;
  const int c = l & 15, g = l >> 4;
  const int b0 = blockIdx.x * 16;
  const uint16_t* gh  = (const uint16_t*)(ws + OFF_GH);
  const uint16_t* gl  = (const uint16_t*)(ws + OFF_GL);
  const uint16_t* h1h = (const uint16_t*)(ws + OFF_H1H);
  const uint16_t* h1l = (const uint16_t*)(ws + OFF_H1L);
  const float* Pz = P;
  const float* Pr = P + (size_t)Tt*Bb*Mh;
  const float* Ph = P + 2*(size_t)Tt*Bb*Mh;

  // resident gate-hi fragments (128 VGPR)
  short8 GH[2][2][8];
  #pragma unroll
  for (int mat = 0; mat < 2; ++mat)
    #pragma unroll
    for (int mtl = 0; mtl < 2; ++mtl)
      #pragma unroll
      for (int kt = 0; kt < 8; ++kt){
        size_t o = ((((size_t)mat*16 + (w*2 + mtl))*8 + kt)*64 + l)*8;
        GH[mat][mtl][kt] = *(const short8*)(gh + o);
      }
  short8 H1H7[2];
  #pragma unroll
  for (int mtl = 0; mtl < 2; ++mtl){
    size_t o = (((size_t)(w*2 + mtl)*8 + 7)*64 + l)*8;
    H1H7[mtl] = *(const short8*)(h1h + o);
  }
  // stage Wh1-hi kt0..6 into LDS (lane-linear frag layout -> conflict-free b128 reads)
  for (int f = w; f < 112; f += 8){
    int mt = f / 7, kt = f % 7;
    float4 v = *(const float4*)(h1h + (((size_t)mt*8 + kt)*64 + l)*8);
    *(float4*)(lds + ((size_t)(mt*7 + kt)*64 + l)*16) = v;
  }
  __syncthreads();

  const int HOFF = 114688, SOFF = 131072;
  const int r = c;                              // A-frag row = lane&15
  const int aswz = (r & 7) << 4;                // XOR swizzle on 16B slots
  const int swA0 = ((r*1024 + g*32) ^ aswz);
  const int swA1 = ((r*1024 + g*32 + 16) ^ aswz);

  // ---- t = 0 : h0 = tanh(Ph[0]) (bias already folded into Ph) ----
  #pragma unroll
  for (int mtl = 0; mtl < 2; ++mtl){
    int m0 = (w*2 + mtl)*16;
    #pragma unroll
    for (int i = 0; i < 4; ++i){
      int brow = 4*g + i;
      float v = Ph[((size_t)0*Bb + (b0 + brow))*Mh + m0 + c];
      float h0 = tanhA(v);
      int ad = ((brow*1024 + (m0 + c)*4) ^ ((brow & 7) << 4));
      *(float*)(lds + HOFF + ad) = h0;
      out[(size_t)(b0 + brow)*Tt*Mh + m0 + c] = h0;
    }
  }
  __syncthreads();

  for (int t = 1; t < Tt; ++t){
    // ---- phase A: gate pre-activations (init acc with P = Wx@x_t + bias) ----
    f32x4 accZ[2], accR[2];
    #pragma unroll
    for (int mtl = 0; mtl < 2; ++mtl){
      int m0 = (w*2 + mtl)*16;
      #pragma unroll
      for (int i = 0; i < 4; ++i){
        size_t pi = (((size_t)t)*Bb + (b0 + 4*g + i))*Mh + m0 + c;
        accZ[mtl][i] = Pz[pi];
        accR[mtl][i] = Pr[pi];
      }
    }
    #pragma unroll
    for (int kt = 0; kt < 8; ++kt){
      float4 v0 = *(const float4*)(lds + HOFF + swA0 + kt*128);
      float4 v1 = *(const float4*)(lds + HOFF + swA1 + kt*128);
      short8 ahi, alo; split8f(v0, v1, ahi, alo);
      #pragma unroll
      for (int mtl = 0; mtl < 2; ++mtl){
        int mt = w*2 + mtl;
        short8 zlo = *(const short8*)(gl + ((((size_t)0*16 + mt)*8 + kt)*64 + l)*8);
        short8 rlo = *(const short8*)(gl + ((((size_t)1*16 + mt)*8 + kt)*64 + l)*8);
        accZ[mtl] = mfma16(ahi, GH[0][mtl][kt], accZ[mtl]);
        accZ[mtl] = mfma16(ahi, zlo,            accZ[mtl]);
        accZ[mtl] = mfma16(alo, GH[0][mtl][kt], accZ[mtl]);
        accR[mtl] = mfma16(ahi, GH[1][mtl][kt], accR[mtl]);
        accR[mtl] = mfma16(ahi, rlo,            accR[mtl]);
        accR[mtl] = mfma16(alo, GH[1][mtl][kt], accR[mtl]);
      }
    }
    // ---- activations, s = r*hp (each wave touches only its own m-columns) ----
    float zv[2][4], hpv[2][4];
    #pragma unroll
    for (int mtl = 0; mtl < 2; ++mtl){
      int m0 = (w*2 + mtl)*16;
      #pragma unroll
      for (int i = 0; i < 4; ++i){
        int brow = 4*g + i;
        int ad = ((brow*1024 + (m0 + c)*4) ^ ((brow & 7) << 4));
        float hp = *(const float*)(lds + HOFF + ad);
        float z  = sigm(accZ[mtl][i]);
        float rr = sigm(accR[mtl][i]);
        zv[mtl][i] = z; hpv[mtl][i] = hp;
        *(float*)(lds + SOFF + ad) = rr * hp;
      }
    }
    __syncthreads();
    // ---- phase B: h_tilde pre-activation (init with Ph = Wh2@x_t + bh) ----
    f32x4 accH[2];
    #pragma unroll
    for (int mtl = 0; mtl < 2; ++mtl){
      int m0 = (w*2 + mtl)*16;
      #pragma unroll
      for (int i = 0; i < 4; ++i)
        accH[mtl][i] = Ph[(((size_t)t)*Bb + (b0 + 4*g + i))*Mh + m0 + c];
    }
    #pragma unroll
    for (int kt = 0; kt < 8; ++kt){
      float4 v0 = *(const float4*)(lds + SOFF + swA0 + kt*128);
      float4 v1 = *(const float4*)(lds + SOFF + swA1 + kt*128);
      short8 shi, slo; split8f(v0, v1, shi, slo);
      #pragma unroll
      for (int mtl = 0; mtl < 2; ++mtl){
        int mt = w*2 + mtl;
        short8 whi = (kt < 7) ? *(const short8*)(lds + ((size_t)(mt*7 + kt)*64 + l)*16)
                              : H1H7[mtl];
        short8 wlo = *(const short8*)(h1l + (((size_t)mt*8 + kt)*64 + l)*8);
        accH[mtl] = mfma16(shi, whi, accH[mtl]);
        accH[mtl] = mfma16(shi, wlo, accH[mtl]);
        accH[mtl] = mfma16(slo, whi, accH[mtl]);
      }
    }
    // ---- blend + write h_t ----
    #pragma unroll
    for (int mtl = 0; mtl < 2; ++mtl){
      int m0 = (w*2 + mtl)*16;
      #pragma unroll
      for (int i = 0; i < 4; ++i){
        int brow = 4*g + i;
        float ht = tanhA(accH[mtl][i]);
        float hn = hpv[mtl][i] + zv[mtl][i] * (ht - hpv[mtl][i]);
        int ad = ((brow*1024 + (m0 + c)*4) ^ ((brow & 7) << 4));
        *(float*)(lds + HOFF + ad) = hn;
        out[(size_t)(b0 + brow)*Tt*Mh + (size_t)t*Mh + m0 + c] = hn;
      }
    }
    __syncthreads();
  }
}

extern "C" void kernel_launch(void* const* d_in, const int* in_sizes, int n_in,
                              void* d_out, int out_size, void* d_ws, size_t ws_size,
                              hipStream_t stream){
  const int*   x    = (const int*)  d_in[0];
  const float* topo = (const float*)d_in[1];
  const float* Wz   = (const float*)d_in[2];
  const float* Wr   = (const float*)d_in[3];
  const float* Wh1  = (const float*)d_in[4];
  const float* Wh2  = (const float*)d_in[5];
  const float* bz   = (const float*)d_in[6];
  const float* br   = (const float*)d_in[7];
  const float* bh   = (const float*)d_in[8];
  uint8_t* ws = (uint8_t*)d_ws;
  float*   P  = (float*)(ws + OFF_P);
  float*   out = (float*)d_out;

  if (ws_size < WS_NEED){
    // workspace too small for P precompute: fail loudly but cleanly
    hipMemsetAsync(d_out, 0, (size_t)out_size * sizeof(float), stream);
    return;
  }
  hipFuncSetAttribute((const void*)gru_kernel,
                      hipFuncAttributeMaxDynamicSharedMemorySize, 147456);

  prep_kernel<<<144, 256, 0, stream>>>(Wz, Wr, Wh1, Wh2, ws);
  proj_kernel<<<256, 512, 0, stream>>>(x, topo, bz, br, bh, ws, P);
  gru_kernel<<<16, 512, 147456, stream>>>(ws, P, out);
}